// Round 8
// baseline (141.455 us; speedup 1.0000x reference)
//
#include <hip/hip_runtime.h>

#define N_NODES 10000
#define N_EDGES 640000
#define D_FEAT 128
#define NGROUPS 8
#define NODES_PER_GROUP (N_NODES / NGROUPS)   // 1250

// ---- ws layout (bytes) ----
#define WS_OFFSETS 0
#define WS_CURSORS 40064
#define WS_CSR     80128

typedef int   iv4 __attribute__((ext_vector_type(4)));
typedef float fv4 __attribute__((ext_vector_type(4)));

// Single-block exclusive scan of (int)deg -> offsets, cursors.
// Coalesced LDS stage + shuffle wave-scan; 3 barriers total.
__global__ __launch_bounds__(1024) void scan_kernel(
    const float* __restrict__ deg,
    int* __restrict__ offsets,
    int* __restrict__ cursors) {
    __shared__ int cnt[10240];     // 40 KB
    __shared__ int wsum[16];
    const int t = threadIdx.x;
    for (int i = t; i < 10240; i += 1024)
        cnt[i] = (i < N_NODES) ? (int)deg[i] : 0;
    __syncthreads();

    const int base_i = t * 10;
    int csum = 0;
    #pragma unroll
    for (int j = 0; j < 10; ++j) csum += cnt[base_i + j];

    const int lane = t & 63, w = t >> 6;
    int incl = csum;
    #pragma unroll
    for (int off = 1; off < 64; off <<= 1) {
        int v = __shfl_up(incl, off);
        if (lane >= off) incl += v;
    }
    if (lane == 63) wsum[w] = incl;
    __syncthreads();

    int wbase = 0;
    #pragma unroll
    for (int i = 0; i < 16; ++i) wbase += (i < w) ? wsum[i] : 0;

    int p = wbase + incl - csum;   // exclusive prefix of this thread's chunk
    #pragma unroll
    for (int j = 0; j < 10; ++j) {
        int i = base_i + j;
        if (i < N_NODES) { offsets[i] = p; cursors[i] = p; }
        p += cnt[i];
    }
}

// Group-partitioned fill. Both index streams loaded as NT int4 (no L2
// pollution, no scattered src fetches); csr stores cached so lines fill
// before writeback.
#define FILL_BLOCKS 2048
#define FILL_THREADS 256
__global__ __launch_bounds__(FILL_THREADS) void fill_kernel(
    const int* __restrict__ src,
    const int* __restrict__ dst,
    int* __restrict__ cursors,
    int* __restrict__ csr) {
    const int b = blockIdx.x;
    const int k = b & 7;
    const int lo = k * NODES_PER_GROUP;
    const int hi = lo + NODES_PER_GROUP;
    const int tg = (b >> 3) * FILL_THREADS + threadIdx.x;   // 0..65535 in group
    const int NV = N_EDGES / 4;                             // 160000
    for (int v = tg; v < NV; v += 65536) {
        iv4 d4 = __builtin_nontemporal_load((const iv4*)dst + v);
        iv4 s4 = __builtin_nontemporal_load((const iv4*)src + v);
        #pragma unroll
        for (int kk = 0; kk < 4; ++kk) {
            const int d = d4[kk];
            if (d >= lo && d < hi) {
                int pos = atomicAdd(&cursors[d], 1);
                csr[pos] = s4[kk];
            }
        }
    }
}

// Gather: 32 lanes per node, 8 nodes per 256-thread block; %8 node grouping
// matches fill so csr reads hit the writing XCD's L2. Unroll-8 for MLP.
#define GATHER_BPG 157                          // ceil(1250/8)
#define GATHER_BLOCKS (GATHER_BPG * NGROUPS)    // 1256
__global__ __launch_bounds__(256) void gather_kernel(
    const float* __restrict__ x,
    const int* __restrict__ offsets,
    const int* __restrict__ cursors,   // post-fill: exact segment ends
    const int* __restrict__ csr,
    const float* __restrict__ deg,
    float* __restrict__ out) {
    const int b = blockIdx.x;
    const int k = b & 7;
    const int r = b >> 3;
    const int g = threadIdx.x >> 5;
    const int lane = threadIdx.x & 31;
    const int nig = r * 8 + g;
    if (nig >= NODES_PER_GROUP) return;
    const int node = k * NODES_PER_GROUP + nig;
    const int f = lane << 2;

    int j = offsets[node];
    const int end = cursors[node];

    fv4 acc = (fv4)0.0f;
    for (; j + 8 <= end; j += 8) {
        int s[8];
        #pragma unroll
        for (int u = 0; u < 8; ++u) s[u] = csr[j + u];
        fv4 v[8];
        #pragma unroll
        for (int u = 0; u < 8; ++u)
            v[u] = *reinterpret_cast<const fv4*>(&x[(size_t)s[u] * D_FEAT + f]);
        fv4 t0 = (v[0] + v[1]) + (v[2] + v[3]);
        fv4 t1 = (v[4] + v[5]) + (v[6] + v[7]);
        acc += t0 + t1;
    }
    for (; j < end; ++j) {
        int s = csr[j];
        acc += *reinterpret_cast<const fv4*>(&x[(size_t)s * D_FEAT + f]);
    }

    const float inv = 1.0f / deg[node];
    fv4 rv = acc * inv;
    __builtin_nontemporal_store(rv, reinterpret_cast<fv4*>(&out[(size_t)node * D_FEAT + f]));
}

extern "C" void kernel_launch(void* const* d_in, const int* in_sizes, int n_in,
                              void* d_out, int out_size, void* d_ws, size_t ws_size,
                              hipStream_t stream) {
    const float* x   = (const float*)d_in[0];
    const int*   ei  = (const int*)d_in[1];   // [2, N_EDGES] flat: src row, dst row
    const float* deg = (const float*)d_in[2];
    float* out = (float*)d_out;

    const int* src = ei;
    const int* dst = ei + N_EDGES;

    char* ws = (char*)d_ws;
    int* offsets = (int*)(ws + WS_OFFSETS);
    int* cursors = (int*)(ws + WS_CURSORS);
    int* csr     = (int*)(ws + WS_CSR);

    scan_kernel<<<1, 1024, 0, stream>>>(deg, offsets, cursors);
    fill_kernel<<<FILL_BLOCKS, FILL_THREADS, 0, stream>>>(src, dst, cursors, csr);
    gather_kernel<<<GATHER_BLOCKS, 256, 0, stream>>>(x, offsets, cursors, csr, deg, out);
}

// Round 9
// 116.647 us; speedup vs baseline: 1.2127x; 1.2127x over previous
//
#include <hip/hip_runtime.h>

#define N_NODES 10000
#define N_EDGES 640000
#define D_FEAT 128
#define NGROUPS 8
#define NPG (N_NODES / NGROUPS)               // 1250 nodes per group

// ---- ws layout (bytes) ----
#define WS_OFFSETS 0
#define WS_CURSORS 40064
#define WS_CSR     80128

typedef int   iv4 __attribute__((ext_vector_type(4)));
typedef float fv4 __attribute__((ext_vector_type(4)));

// Single-block exclusive scan of (int)deg -> offsets, cursors.
__global__ __launch_bounds__(1024) void scan_kernel(
    const float* __restrict__ deg,
    int* __restrict__ offsets,
    int* __restrict__ cursors) {
    __shared__ int cnt[10240];     // 40 KB
    __shared__ int wsum[16];
    const int t = threadIdx.x;
    for (int i = t; i < 10240; i += 1024)
        cnt[i] = (i < N_NODES) ? (int)deg[i] : 0;
    __syncthreads();

    const int base_i = t * 10;
    int csum = 0;
    #pragma unroll
    for (int j = 0; j < 10; ++j) csum += cnt[base_i + j];

    const int lane = t & 63, w = t >> 6;
    int incl = csum;
    #pragma unroll
    for (int off = 1; off < 64; off <<= 1) {
        int v = __shfl_up(incl, off);
        if (lane >= off) incl += v;
    }
    if (lane == 63) wsum[w] = incl;
    __syncthreads();

    int wbase = 0;
    #pragma unroll
    for (int i = 0; i < 16; ++i) wbase += (i < w) ? wsum[i] : 0;

    int p = wbase + incl - csum;
    #pragma unroll
    for (int j = 0; j < 10; ++j) {
        int i = base_i + j;
        if (i < N_NODES) { offsets[i] = p; cursors[i] = p; }
        p += cnt[i];
    }
}

// Two-pass fill: LDS histogram -> bulk range reservation (1 global atomic per
// touched node per block) -> placement with LDS cursors. Global atomics drop
// 640k -> ~157k and per-edge atomics become LDS-local.
#define FILL_THREADS 1024
#define NCHUNKS_F 16
#define FILL_BLOCKS (NGROUPS * NCHUNKS_F)       // 128
#define IV4_PER_CHUNK (N_EDGES / NCHUNKS_F / 4) // 10000
__global__ __launch_bounds__(FILL_THREADS) void fill_kernel(
    const int* __restrict__ src,
    const int* __restrict__ dst,
    int* __restrict__ cursors,
    int* __restrict__ csr) {
    __shared__ int cnt[NPG];
    __shared__ int base[NPG];
    const int b = blockIdx.x;
    const int k = b & 7;            // group -> csr slice (XCD-local if %8 maps)
    const int c = b >> 3;           // chunk 0..15
    const int lo = k * NPG;
    const int t = threadIdx.x;
    const int v0 = c * IV4_PER_CHUNK;

    for (int i = t; i < NPG; i += FILL_THREADS) cnt[i] = 0;
    __syncthreads();

    // Pass A: histogram of this chunk's matched dst (dst stays L2-cached).
    for (int v = t; v < IV4_PER_CHUNK; v += FILL_THREADS) {
        iv4 d4 = ((const iv4*)dst)[v0 + v];
        #pragma unroll
        for (int kk = 0; kk < 4; ++kk) {
            int ln = d4[kk] - lo;
            if ((unsigned)ln < (unsigned)NPG) atomicAdd(&cnt[ln], 1);
        }
    }
    __syncthreads();

    // Bulk reservation: one global atomic per touched node.
    for (int i = t; i < NPG; i += FILL_THREADS) {
        int cc = cnt[i];
        base[i] = cc ? atomicAdd(&cursors[lo + i], cc) : 0;
        cnt[i] = 0;                 // reuse as local cursor
    }
    __syncthreads();

    // Pass B: place edges. dst re-read hits L2; src is single-use (NT).
    for (int v = t; v < IV4_PER_CHUNK; v += FILL_THREADS) {
        iv4 d4 = ((const iv4*)dst)[v0 + v];
        iv4 s4 = __builtin_nontemporal_load((const iv4*)src + v0 + v);
        #pragma unroll
        for (int kk = 0; kk < 4; ++kk) {
            int ln = d4[kk] - lo;
            if ((unsigned)ln < (unsigned)NPG) {
                int slot = base[ln] + atomicAdd(&cnt[ln], 1);
                csr[slot] = s4[kk];
            }
        }
    }
}

// Gather: 32 lanes/node, 8 nodes per 256-thread block; %8 grouping matches
// fill so csr reads hit the writing XCD's L2. Unroll-16 for deep MLP.
#define GATHER_BPG 157
#define GATHER_BLOCKS (GATHER_BPG * NGROUPS)    // 1256
__global__ __launch_bounds__(256) void gather_kernel(
    const float* __restrict__ x,
    const int* __restrict__ offsets,
    const int* __restrict__ cursors,   // post-fill: exact segment ends
    const int* __restrict__ csr,
    const float* __restrict__ deg,
    float* __restrict__ out) {
    const int b = blockIdx.x;
    const int k = b & 7;
    const int r = b >> 3;
    const int g = threadIdx.x >> 5;
    const int lane = threadIdx.x & 31;
    const int nig = r * 8 + g;
    if (nig >= NPG) return;
    const int node = k * NPG + nig;
    const int f = lane << 2;

    int j = offsets[node];
    const int end = cursors[node];

    fv4 acc = (fv4)0.0f;
    for (; j + 16 <= end; j += 16) {
        int s[16];
        #pragma unroll
        for (int u = 0; u < 16; ++u) s[u] = csr[j + u];
        fv4 v[16];
        #pragma unroll
        for (int u = 0; u < 16; ++u)
            v[u] = *reinterpret_cast<const fv4*>(&x[(size_t)s[u] * D_FEAT + f]);
        fv4 t0 = (v[0] + v[1]) + (v[2] + v[3]);
        fv4 t1 = (v[4] + v[5]) + (v[6] + v[7]);
        fv4 t2 = (v[8] + v[9]) + (v[10] + v[11]);
        fv4 t3 = (v[12] + v[13]) + (v[14] + v[15]);
        acc += (t0 + t1) + (t2 + t3);
    }
    for (; j + 4 <= end; j += 4) {
        int s0 = csr[j], s1 = csr[j + 1], s2 = csr[j + 2], s3 = csr[j + 3];
        fv4 a = *reinterpret_cast<const fv4*>(&x[(size_t)s0 * D_FEAT + f]);
        fv4 bb = *reinterpret_cast<const fv4*>(&x[(size_t)s1 * D_FEAT + f]);
        fv4 cc = *reinterpret_cast<const fv4*>(&x[(size_t)s2 * D_FEAT + f]);
        fv4 dd = *reinterpret_cast<const fv4*>(&x[(size_t)s3 * D_FEAT + f]);
        acc += (a + bb) + (cc + dd);
    }
    for (; j < end; ++j)
        acc += *reinterpret_cast<const fv4*>(&x[(size_t)csr[j] * D_FEAT + f]);

    const float inv = 1.0f / deg[node];
    fv4 rv = acc * inv;
    __builtin_nontemporal_store(rv, reinterpret_cast<fv4*>(&out[(size_t)node * D_FEAT + f]));
}

extern "C" void kernel_launch(void* const* d_in, const int* in_sizes, int n_in,
                              void* d_out, int out_size, void* d_ws, size_t ws_size,
                              hipStream_t stream) {
    const float* x   = (const float*)d_in[0];
    const int*   ei  = (const int*)d_in[1];   // [2, N_EDGES] flat: src row, dst row
    const float* deg = (const float*)d_in[2];
    float* out = (float*)d_out;

    const int* src = ei;
    const int* dst = ei + N_EDGES;

    char* ws = (char*)d_ws;
    int* offsets = (int*)(ws + WS_OFFSETS);
    int* cursors = (int*)(ws + WS_CURSORS);
    int* csr     = (int*)(ws + WS_CSR);

    scan_kernel<<<1, 1024, 0, stream>>>(deg, offsets, cursors);
    fill_kernel<<<FILL_BLOCKS, FILL_THREADS, 0, stream>>>(src, dst, cursors, csr);
    gather_kernel<<<GATHER_BLOCKS, 256, 0, stream>>>(x, offsets, cursors, csr, deg, out);
}

// Round 10
// 114.143 us; speedup vs baseline: 1.2393x; 1.0219x over previous
//
#include <hip/hip_runtime.h>

#define N_NODES 10000
#define N_EDGES 640000
#define D_FEAT 128
#define NGROUPS 8
#define NPG (N_NODES / NGROUPS)   // 1250
#define STRIDE 256                // padded CSR slots per node (max deg << 256)

// ---- ws layout (bytes) ----
#define WS_CURSORS 0              // int[10000]
#define WS_CSR     40960          // int[10000*256] = 10.24 MB

typedef int   iv4 __attribute__((ext_vector_type(4)));
typedef float fv4 __attribute__((ext_vector_type(4)));

// Two-pass fill into fixed-stride CSR: LDS histogram -> bulk reservation
// (1 global atomic per touched node per block) -> placement via LDS cursors.
#define FILL_THREADS 1024
#define NCHUNKS_F 16
#define FILL_BLOCKS (NGROUPS * NCHUNKS_F)       // 128
#define IV4_PER_CHUNK (N_EDGES / NCHUNKS_F / 4) // 10000
__global__ __launch_bounds__(FILL_THREADS) void fill_kernel(
    const int* __restrict__ src,
    const int* __restrict__ dst,
    int* __restrict__ cursors,
    int* __restrict__ csr) {
    __shared__ int cnt[NPG];
    __shared__ int base[NPG];
    const int b = blockIdx.x;
    const int k = b & 7;            // group -> csr slice (XCD-local if %8 maps)
    const int c = b >> 3;           // chunk 0..15
    const int lo = k * NPG;
    const int t = threadIdx.x;
    const int v0 = c * IV4_PER_CHUNK;

    for (int i = t; i < NPG; i += FILL_THREADS) cnt[i] = 0;
    __syncthreads();

    // Pass A: histogram of this chunk's matched dst (dst stays L2-cached).
    for (int v = t; v < IV4_PER_CHUNK; v += FILL_THREADS) {
        iv4 d4 = ((const iv4*)dst)[v0 + v];
        #pragma unroll
        for (int kk = 0; kk < 4; ++kk) {
            int ln = d4[kk] - lo;
            if ((unsigned)ln < (unsigned)NPG) atomicAdd(&cnt[ln], 1);
        }
    }
    __syncthreads();

    // Bulk reservation into fixed-stride segment.
    for (int i = t; i < NPG; i += FILL_THREADS) {
        int cc = cnt[i];
        int off = cc ? atomicAdd(&cursors[lo + i], cc) : 0;
        base[i] = (lo + i) * STRIDE + off;
        cnt[i] = 0;                 // reuse as local cursor
    }
    __syncthreads();

    // Pass B: place edges. dst re-read hits L2; src single-use (NT).
    for (int v = t; v < IV4_PER_CHUNK; v += FILL_THREADS) {
        iv4 d4 = ((const iv4*)dst)[v0 + v];
        iv4 s4 = __builtin_nontemporal_load((const iv4*)src + v0 + v);
        #pragma unroll
        for (int kk = 0; kk < 4; ++kk) {
            int ln = d4[kk] - lo;
            if ((unsigned)ln < (unsigned)NPG) {
                int slot = base[ln] + atomicAdd(&cnt[ln], 1);
                csr[slot] = s4[kk];
            }
        }
    }
}

// Gather: 32 lanes/node, 8 nodes per 256-thread block; %8 grouping matches
// fill so csr reads hit the writing XCD's L2. int4 index loads (segments are
// 16-int aligned) + next-batch index prefetch to break the dependent chain.
#define GATHER_BPG 157
#define GATHER_BLOCKS (GATHER_BPG * NGROUPS)    // 1256

#define ROWSUM16(I0, I1, I2, I3)                                        \
    {                                                                   \
        fv4 v[16];                                                      \
        _Pragma("unroll")                                               \
        for (int u = 0; u < 4; ++u) {                                   \
            v[u]      = *(const fv4*)(&x[(size_t)(I0)[u] * D_FEAT + f]);\
            v[4 + u]  = *(const fv4*)(&x[(size_t)(I1)[u] * D_FEAT + f]);\
            v[8 + u]  = *(const fv4*)(&x[(size_t)(I2)[u] * D_FEAT + f]);\
            v[12 + u] = *(const fv4*)(&x[(size_t)(I3)[u] * D_FEAT + f]);\
        }                                                               \
        fv4 t0 = (v[0] + v[1]) + (v[2] + v[3]);                         \
        fv4 t1 = (v[4] + v[5]) + (v[6] + v[7]);                         \
        fv4 t2 = (v[8] + v[9]) + (v[10] + v[11]);                       \
        fv4 t3 = (v[12] + v[13]) + (v[14] + v[15]);                     \
        acc += (t0 + t1) + (t2 + t3);                                   \
    }

__global__ __launch_bounds__(256) void gather_kernel(
    const float* __restrict__ x,
    const int* __restrict__ cursors,   // post-fill: exact per-node counts
    const int* __restrict__ csr,
    const float* __restrict__ deg,
    float* __restrict__ out) {
    const int b = blockIdx.x;
    const int k = b & 7;
    const int r = b >> 3;
    const int g = threadIdx.x >> 5;
    const int lane = threadIdx.x & 31;
    const int nig = r * 8 + g;
    if (nig >= NPG) return;
    const int node = k * NPG + nig;
    const int f = lane << 2;

    const int count = cursors[node];
    const int jbase = node * STRIDE;
    const int end = jbase + count;

    fv4 acc = (fv4)0.0f;
    int j = jbase;

    if (j + 16 <= end) {
        iv4 i0 = *(const iv4*)(csr + j);
        iv4 i1 = *(const iv4*)(csr + j + 4);
        iv4 i2 = *(const iv4*)(csr + j + 8);
        iv4 i3 = *(const iv4*)(csr + j + 12);
        for (; j + 32 <= end; j += 16) {
            // prefetch next batch's indices before using current rows
            iv4 n0 = *(const iv4*)(csr + j + 16);
            iv4 n1 = *(const iv4*)(csr + j + 20);
            iv4 n2 = *(const iv4*)(csr + j + 24);
            iv4 n3 = *(const iv4*)(csr + j + 28);
            ROWSUM16(i0, i1, i2, i3)
            i0 = n0; i1 = n1; i2 = n2; i3 = n3;
        }
        ROWSUM16(i0, i1, i2, i3)
        j += 16;
    }
    for (; j < end; ++j)
        acc += *(const fv4*)(&x[(size_t)csr[j] * D_FEAT + f]);

    const float inv = 1.0f / deg[node];
    fv4 rv = acc * inv;
    __builtin_nontemporal_store(rv, (fv4*)(&out[(size_t)node * D_FEAT + f]));
}

extern "C" void kernel_launch(void* const* d_in, const int* in_sizes, int n_in,
                              void* d_out, int out_size, void* d_ws, size_t ws_size,
                              hipStream_t stream) {
    const float* x   = (const float*)d_in[0];
    const int*   ei  = (const int*)d_in[1];   // [2, N_EDGES] flat: src row, dst row
    const float* deg = (const float*)d_in[2];
    float* out = (float*)d_out;

    const int* src = ei;
    const int* dst = ei + N_EDGES;

    char* ws = (char*)d_ws;
    int* cursors = (int*)(ws + WS_CURSORS);
    int* csr     = (int*)(ws + WS_CSR);

    hipMemsetAsync(cursors, 0, N_NODES * sizeof(int), stream);
    fill_kernel<<<FILL_BLOCKS, FILL_THREADS, 0, stream>>>(src, dst, cursors, csr);
    gather_kernel<<<GATHER_BLOCKS, 256, 0, stream>>>(x, cursors, csr, deg, out);
}

// Round 11
// 104.498 us; speedup vs baseline: 1.3537x; 1.0923x over previous
//
#include <hip/hip_runtime.h>

#define N_NODES 10000
#define N_EDGES 640000
#define D_FEAT 128
#define NGROUPS 8
#define NPG (N_NODES / NGROUPS)   // 1250
#define STRIDE 256                // padded CSR slots per node (max deg ~100 << 256)

// ---- ws layout (bytes) ----
#define WS_CURSORS 0                        // int[10000]
#define WS_CSR     40960                    // int[2,560,000] = 10.24 MB
#define WS_X16     (40960 + 10240000)       // _Float16[1,280,000] = 2.56 MB (16B aligned)

typedef int      iv4 __attribute__((ext_vector_type(4)));
typedef float    fv4 __attribute__((ext_vector_type(4)));
typedef float    fv8 __attribute__((ext_vector_type(8)));
typedef _Float16 hv8 __attribute__((ext_vector_type(8)));

// x (fp32) -> x16 (fp16), 8 elems/thread. 1.28M elems = 625 blocks x 256.
__global__ __launch_bounds__(256) void convert_kernel(
    const float* __restrict__ x, _Float16* __restrict__ x16) {
    const int i = blockIdx.x * 256 + threadIdx.x;
    fv8 v = *(const fv8*)(x + (size_t)i * 8);
    hv8 h = __builtin_convertvector(v, hv8);
    *(hv8*)(x16 + (size_t)i * 8) = h;
}

// Two-pass fill into fixed-stride CSR: LDS histogram -> bulk reservation
// (1 global atomic per touched node per block) -> placement via LDS cursors.
#define FILL_THREADS 1024
#define NCHUNKS_F 16
#define FILL_BLOCKS (NGROUPS * NCHUNKS_F)       // 128
#define IV4_PER_CHUNK (N_EDGES / NCHUNKS_F / 4) // 10000
__global__ __launch_bounds__(FILL_THREADS) void fill_kernel(
    const int* __restrict__ src,
    const int* __restrict__ dst,
    int* __restrict__ cursors,
    int* __restrict__ csr) {
    __shared__ int cnt[NPG];
    __shared__ int base[NPG];
    const int b = blockIdx.x;
    const int k = b & 7;            // group -> csr slice (XCD-local if %8 maps)
    const int c = b >> 3;           // chunk 0..15
    const int lo = k * NPG;
    const int t = threadIdx.x;
    const int v0 = c * IV4_PER_CHUNK;

    for (int i = t; i < NPG; i += FILL_THREADS) cnt[i] = 0;
    __syncthreads();

    for (int v = t; v < IV4_PER_CHUNK; v += FILL_THREADS) {
        iv4 d4 = ((const iv4*)dst)[v0 + v];
        #pragma unroll
        for (int kk = 0; kk < 4; ++kk) {
            int ln = d4[kk] - lo;
            if ((unsigned)ln < (unsigned)NPG) atomicAdd(&cnt[ln], 1);
        }
    }
    __syncthreads();

    for (int i = t; i < NPG; i += FILL_THREADS) {
        int cc = cnt[i];
        int off = cc ? atomicAdd(&cursors[lo + i], cc) : 0;
        base[i] = (lo + i) * STRIDE + off;
        cnt[i] = 0;                 // reuse as local cursor
    }
    __syncthreads();

    for (int v = t; v < IV4_PER_CHUNK; v += FILL_THREADS) {
        iv4 d4 = ((const iv4*)dst)[v0 + v];
        iv4 s4 = __builtin_nontemporal_load((const iv4*)src + v0 + v);
        #pragma unroll
        for (int kk = 0; kk < 4; ++kk) {
            int ln = d4[kk] - lo;
            if ((unsigned)ln < (unsigned)NPG) {
                int slot = base[ln] + atomicAdd(&cnt[ln], 1);
                csr[slot] = s4[kk];
            }
        }
    }
}

// Gather on fp16 rows: 16 lanes/node (hv8 = 16B loads), 16 nodes per
// 256-thread block; %8 grouping matches fill so csr + x16 stay XCD-L2-hot.
#define GBPG 79                               // ceil(1250/16)
#define GATHER_BLOCKS (GBPG * NGROUPS)        // 632

#define CV(H) __builtin_convertvector((H), fv8)

#define ROWSUM16(I0, I1, I2, I3)                                             \
    {                                                                        \
        hv8 h[16];                                                           \
        _Pragma("unroll")                                                    \
        for (int u = 0; u < 4; ++u) {                                        \
            h[u]      = *(const hv8*)(x16 + (size_t)(I0)[u] * D_FEAT + f);   \
            h[4 + u]  = *(const hv8*)(x16 + (size_t)(I1)[u] * D_FEAT + f);   \
            h[8 + u]  = *(const hv8*)(x16 + (size_t)(I2)[u] * D_FEAT + f);   \
            h[12 + u] = *(const hv8*)(x16 + (size_t)(I3)[u] * D_FEAT + f);   \
        }                                                                    \
        fv8 t0 = (CV(h[0]) + CV(h[1])) + (CV(h[2]) + CV(h[3]));              \
        fv8 t1 = (CV(h[4]) + CV(h[5])) + (CV(h[6]) + CV(h[7]));              \
        fv8 t2 = (CV(h[8]) + CV(h[9])) + (CV(h[10]) + CV(h[11]));            \
        fv8 t3 = (CV(h[12]) + CV(h[13])) + (CV(h[14]) + CV(h[15]));          \
        acc += (t0 + t1) + (t2 + t3);                                        \
    }

__global__ __launch_bounds__(256) void gather_kernel(
    const _Float16* __restrict__ x16,
    const int* __restrict__ cursors,   // post-fill: exact per-node counts
    const int* __restrict__ csr,
    const float* __restrict__ deg,
    float* __restrict__ out) {
    const int b = blockIdx.x;
    const int k = b & 7;
    const int r = b >> 3;
    const int g = threadIdx.x >> 4;     // node-in-block 0..15
    const int lane = threadIdx.x & 15;
    const int nig = r * 16 + g;
    if (nig >= NPG) return;
    const int node = k * NPG + nig;
    const int f = lane << 3;            // 8 features per lane

    const int count = cursors[node];
    int j = node * STRIDE;
    const int end = j + count;

    fv8 acc = (fv8)0.0f;

    if (j + 16 <= end) {
        iv4 i0 = *(const iv4*)(csr + j);
        iv4 i1 = *(const iv4*)(csr + j + 4);
        iv4 i2 = *(const iv4*)(csr + j + 8);
        iv4 i3 = *(const iv4*)(csr + j + 12);
        for (; j + 32 <= end; j += 16) {
            iv4 n0 = *(const iv4*)(csr + j + 16);
            iv4 n1 = *(const iv4*)(csr + j + 20);
            iv4 n2 = *(const iv4*)(csr + j + 24);
            iv4 n3 = *(const iv4*)(csr + j + 28);
            ROWSUM16(i0, i1, i2, i3)
            i0 = n0; i1 = n1; i2 = n2; i3 = n3;
        }
        ROWSUM16(i0, i1, i2, i3)
        j += 16;
    }
    for (; j < end; ++j) {
        hv8 h = *(const hv8*)(x16 + (size_t)csr[j] * D_FEAT + f);
        acc += CV(h);
    }

    const float inv = 1.0f / deg[node];
    fv8 rv = acc * inv;
    __builtin_nontemporal_store(rv, (fv8*)(&out[(size_t)node * D_FEAT + f]));
}

extern "C" void kernel_launch(void* const* d_in, const int* in_sizes, int n_in,
                              void* d_out, int out_size, void* d_ws, size_t ws_size,
                              hipStream_t stream) {
    const float* x   = (const float*)d_in[0];
    const int*   ei  = (const int*)d_in[1];   // [2, N_EDGES] flat: src row, dst row
    const float* deg = (const float*)d_in[2];
    float* out = (float*)d_out;

    const int* src = ei;
    const int* dst = ei + N_EDGES;

    char* ws = (char*)d_ws;
    int*       cursors = (int*)(ws + WS_CURSORS);
    int*       csr     = (int*)(ws + WS_CSR);
    _Float16*  x16     = (_Float16*)(ws + WS_X16);

    hipMemsetAsync(cursors, 0, N_NODES * sizeof(int), stream);
    convert_kernel<<<(N_NODES * D_FEAT) / (256 * 8), 256, 0, stream>>>(x, x16);
    fill_kernel<<<FILL_BLOCKS, FILL_THREADS, 0, stream>>>(src, dst, cursors, csr);
    gather_kernel<<<GATHER_BLOCKS, 256, 0, stream>>>(x16, cursors, csr, deg, out);
}

// Round 12
// 101.683 us; speedup vs baseline: 1.3911x; 1.0277x over previous
//
#include <hip/hip_runtime.h>

#define N_NODES 10000
#define N_EDGES 640000
#define D_FEAT 128
#define NGROUPS 8
#define NPG (N_NODES / NGROUPS)   // 1250
#define STRIDE 256                // padded CSR slots per node (max deg ~100 << 256)

// ---- ws layout (bytes) ----
#define WS_CURSORS 0                        // int[10000]
#define WS_CSR     40960                    // int[2,560,000] = 10.24 MB
#define WS_X16     (40960 + 10240000)       // _Float16[1,280,000] = 2.56 MB (16B aligned)

typedef int      iv4 __attribute__((ext_vector_type(4)));
typedef float    fv8 __attribute__((ext_vector_type(8)));
typedef _Float16 hv8 __attribute__((ext_vector_type(8)));

// Hybrid kernel: blocks 0..127 build the CSR (two-pass fill, proven r9-r11);
// blocks 128.. run the fp32->fp16 convert concurrently (independent outputs).
#define FILL_BLOCKS 128
#define NCHUNKS_F 16
#define IV4_PER_CHUNK (N_EDGES / NCHUNKS_F / 4) // 10000
#define CONV_V8 (N_NODES * D_FEAT / 8)          // 160000 fv8 elements
#define CONV_BLOCKS ((CONV_V8 + 1023) / 1024)   // 157
#define HYBRID_BLOCKS (FILL_BLOCKS + CONV_BLOCKS)

__global__ __launch_bounds__(1024) void hybrid_kernel(
    const float* __restrict__ x,
    _Float16* __restrict__ x16,
    const int* __restrict__ src,
    const int* __restrict__ dst,
    int* __restrict__ cursors,
    int* __restrict__ csr) {
    const int b = blockIdx.x;
    const int t = threadIdx.x;

    if (b >= FILL_BLOCKS) {
        // ---- convert role ----
        const int i = (b - FILL_BLOCKS) * 1024 + t;
        if (i < CONV_V8) {
            fv8 v = *(const fv8*)(x + (size_t)i * 8);
            *(hv8*)(x16 + (size_t)i * 8) = __builtin_convertvector(v, hv8);
        }
        return;
    }

    // ---- fill role: two-pass fill into fixed-stride CSR ----
    __shared__ int cnt[NPG];
    __shared__ int base[NPG];
    const int k = b & 7;            // group -> csr slice (XCD-local if %8 maps)
    const int c = b >> 3;           // chunk 0..15
    const int lo = k * NPG;
    const int v0 = c * IV4_PER_CHUNK;

    for (int i = t; i < NPG; i += 1024) cnt[i] = 0;
    __syncthreads();

    // Pass A: histogram matched dst of this chunk (dst stays cached).
    for (int v = t; v < IV4_PER_CHUNK; v += 1024) {
        iv4 d4 = ((const iv4*)dst)[v0 + v];
        #pragma unroll
        for (int kk = 0; kk < 4; ++kk) {
            int ln = d4[kk] - lo;
            if ((unsigned)ln < (unsigned)NPG) atomicAdd(&cnt[ln], 1);
        }
    }
    __syncthreads();

    // Bulk reservation: one global atomic per touched node.
    for (int i = t; i < NPG; i += 1024) {
        int cc = cnt[i];
        int off = cc ? atomicAdd(&cursors[lo + i], cc) : 0;
        base[i] = (lo + i) * STRIDE + off;
        cnt[i] = 0;                 // reuse as local cursor
    }
    __syncthreads();

    // Pass B: place edges. dst re-read is L1/L2-hot; src single-use (NT).
    for (int v = t; v < IV4_PER_CHUNK; v += 1024) {
        iv4 d4 = ((const iv4*)dst)[v0 + v];
        iv4 s4 = __builtin_nontemporal_load((const iv4*)src + v0 + v);
        #pragma unroll
        for (int kk = 0; kk < 4; ++kk) {
            int ln = d4[kk] - lo;
            if ((unsigned)ln < (unsigned)NPG) {
                int slot = base[ln] + atomicAdd(&cnt[ln], 1);
                csr[slot] = s4[kk];
            }
        }
    }
}

// Gather on fp16 rows: 16 lanes/node (hv8 = 16B loads), 16 nodes per
// 256-thread block; %8 grouping matches fill so csr + x16 stay XCD-L2-hot.
#define GBPG 79                               // ceil(1250/16)
#define GATHER_BLOCKS (GBPG * NGROUPS)        // 632

#define CV(H) __builtin_convertvector((H), fv8)

#define ROWSUM16(I0, I1, I2, I3)                                             \
    {                                                                        \
        hv8 h[16];                                                           \
        _Pragma("unroll")                                                    \
        for (int u = 0; u < 4; ++u) {                                        \
            h[u]      = *(const hv8*)(x16 + (size_t)(I0)[u] * D_FEAT + f);   \
            h[4 + u]  = *(const hv8*)(x16 + (size_t)(I1)[u] * D_FEAT + f);   \
            h[8 + u]  = *(const hv8*)(x16 + (size_t)(I2)[u] * D_FEAT + f);   \
            h[12 + u] = *(const hv8*)(x16 + (size_t)(I3)[u] * D_FEAT + f);   \
        }                                                                    \
        fv8 t0 = (CV(h[0]) + CV(h[1])) + (CV(h[2]) + CV(h[3]));              \
        fv8 t1 = (CV(h[4]) + CV(h[5])) + (CV(h[6]) + CV(h[7]));              \
        fv8 t2 = (CV(h[8]) + CV(h[9])) + (CV(h[10]) + CV(h[11]));            \
        fv8 t3 = (CV(h[12]) + CV(h[13])) + (CV(h[14]) + CV(h[15]));          \
        acc += (t0 + t1) + (t2 + t3);                                        \
    }

__global__ __launch_bounds__(256) void gather_kernel(
    const _Float16* __restrict__ x16,
    const int* __restrict__ cursors,   // post-fill: exact per-node counts
    const int* __restrict__ csr,
    const float* __restrict__ deg,
    float* __restrict__ out) {
    const int b = blockIdx.x;
    const int k = b & 7;
    const int r = b >> 3;
    const int g = threadIdx.x >> 4;     // node-in-block 0..15
    const int lane = threadIdx.x & 15;
    const int nig = r * 16 + g;
    if (nig >= NPG) return;
    const int node = k * NPG + nig;
    const int f = lane << 3;            // 8 features per lane

    const int count = cursors[node];
    int j = node * STRIDE;
    const int end = j + count;

    fv8 acc = (fv8)0.0f;

    if (j + 16 <= end) {
        iv4 i0 = *(const iv4*)(csr + j);
        iv4 i1 = *(const iv4*)(csr + j + 4);
        iv4 i2 = *(const iv4*)(csr + j + 8);
        iv4 i3 = *(const iv4*)(csr + j + 12);
        for (; j + 32 <= end; j += 16) {
            iv4 n0 = *(const iv4*)(csr + j + 16);
            iv4 n1 = *(const iv4*)(csr + j + 20);
            iv4 n2 = *(const iv4*)(csr + j + 24);
            iv4 n3 = *(const iv4*)(csr + j + 28);
            ROWSUM16(i0, i1, i2, i3)
            i0 = n0; i1 = n1; i2 = n2; i3 = n3;
        }
        ROWSUM16(i0, i1, i2, i3)
        j += 16;
    }
    for (; j < end; ++j) {
        hv8 h = *(const hv8*)(x16 + (size_t)csr[j] * D_FEAT + f);
        acc += CV(h);
    }

    const float inv = 1.0f / deg[node];
    fv8 rv = acc * inv;
    __builtin_nontemporal_store(rv, (fv8*)(&out[(size_t)node * D_FEAT + f]));
}

extern "C" void kernel_launch(void* const* d_in, const int* in_sizes, int n_in,
                              void* d_out, int out_size, void* d_ws, size_t ws_size,
                              hipStream_t stream) {
    const float* x   = (const float*)d_in[0];
    const int*   ei  = (const int*)d_in[1];   // [2, N_EDGES] flat: src row, dst row
    const float* deg = (const float*)d_in[2];
    float* out = (float*)d_out;

    const int* src = ei;
    const int* dst = ei + N_EDGES;

    char* ws = (char*)d_ws;
    int*       cursors = (int*)(ws + WS_CURSORS);
    int*       csr     = (int*)(ws + WS_CSR);
    _Float16*  x16     = (_Float16*)(ws + WS_X16);

    hipMemsetAsync(cursors, 0, N_NODES * sizeof(int), stream);
    hybrid_kernel<<<HYBRID_BLOCKS, 1024, 0, stream>>>(x, x16, src, dst, cursors, csr);
    gather_kernel<<<GATHER_BLOCKS, 256, 0, stream>>>(x16, cursors, csr, deg, out);
}

// Round 13
// 94.849 us; speedup vs baseline: 1.4914x; 1.0721x over previous
//
#include <hip/hip_runtime.h>

#define N_NODES 10000
#define N_EDGES 640000
#define D_FEAT 128
#define NGROUPS 8
#define NPG (N_NODES / NGROUPS)   // 1250
#define STRIDE 256                // padded CSR slots per node (max deg ~100 << 256)

// ---- ws layout (bytes) ----
#define WS_CURSORS 0                        // int[10000]
#define WS_CSR     40960                    // int[2,560,000] = 10.24 MB
#define WS_X16     (40960 + 10240000)       // _Float16[1,280,000] = 2.56 MB (16B aligned)

typedef int      iv4 __attribute__((ext_vector_type(4)));
typedef float    fv8 __attribute__((ext_vector_type(8)));
typedef _Float16 hv8 __attribute__((ext_vector_type(8)));

// Hybrid kernel: blocks 0..511 build the CSR (two-pass fill; algorithm proven
// r9-r12, now at 512 threads x 512 blocks for full-CU occupancy & phase
// overlap); remaining blocks run the fp32->fp16 convert concurrently.
#define FILL_THREADS 512
#define FILL_BLOCKS 512
#define NCHUNKS_F 64
#define IV4_PER_CHUNK (N_EDGES / NCHUNKS_F / 4)        // 2500
#define CONV_V8 (N_NODES * D_FEAT / 8)                 // 160000 fv8 elements
#define CONV_BLOCKS ((CONV_V8 + FILL_THREADS - 1) / FILL_THREADS)  // 313
#define HYBRID_BLOCKS (FILL_BLOCKS + CONV_BLOCKS)

__global__ __launch_bounds__(FILL_THREADS) void hybrid_kernel(
    const float* __restrict__ x,
    _Float16* __restrict__ x16,
    const int* __restrict__ src,
    const int* __restrict__ dst,
    int* __restrict__ cursors,
    int* __restrict__ csr) {
    const int b = blockIdx.x;
    const int t = threadIdx.x;

    if (b >= FILL_BLOCKS) {
        // ---- convert role ----
        const int i = (b - FILL_BLOCKS) * FILL_THREADS + t;
        if (i < CONV_V8) {
            fv8 v = *(const fv8*)(x + (size_t)i * 8);
            *(hv8*)(x16 + (size_t)i * 8) = __builtin_convertvector(v, hv8);
        }
        return;
    }

    // ---- fill role: two-pass fill into fixed-stride CSR ----
    __shared__ int cnt[NPG];
    __shared__ int base[NPG];
    const int k = b & 7;            // group -> csr slice (XCD-local if %8 maps)
    const int c = b >> 3;           // chunk 0..63
    const int lo = k * NPG;
    const int v0 = c * IV4_PER_CHUNK;

    for (int i = t; i < NPG; i += FILL_THREADS) cnt[i] = 0;
    __syncthreads();

    // Pass A: histogram matched dst of this chunk (cached; L3 serves replicas).
    for (int v = t; v < IV4_PER_CHUNK; v += FILL_THREADS) {
        iv4 d4 = ((const iv4*)dst)[v0 + v];
        #pragma unroll
        for (int kk = 0; kk < 4; ++kk) {
            int ln = d4[kk] - lo;
            if ((unsigned)ln < (unsigned)NPG) atomicAdd(&cnt[ln], 1);
        }
    }
    __syncthreads();

    // Bulk reservation: one global atomic per touched node.
    for (int i = t; i < NPG; i += FILL_THREADS) {
        int cc = cnt[i];
        int off = cc ? atomicAdd(&cursors[lo + i], cc) : 0;
        base[i] = (lo + i) * STRIDE + off;
        cnt[i] = 0;                 // reuse as local cursor
    }
    __syncthreads();

    // Pass B: place edges (dst re-read L1/L2-hot; src cached, L3-replicated).
    for (int v = t; v < IV4_PER_CHUNK; v += FILL_THREADS) {
        iv4 d4 = ((const iv4*)dst)[v0 + v];
        iv4 s4 = ((const iv4*)src)[v0 + v];
        #pragma unroll
        for (int kk = 0; kk < 4; ++kk) {
            int ln = d4[kk] - lo;
            if ((unsigned)ln < (unsigned)NPG) {
                int slot = base[ln] + atomicAdd(&cnt[ln], 1);
                csr[slot] = s4[kk];
            }
        }
    }
}

// Gather on fp16 rows: 16 lanes/node (hv8 = 16B loads), 16 nodes per
// 256-thread block; %8 grouping matches fill so csr + x16 stay XCD-L2-hot.
#define GBPG 79                               // ceil(1250/16)
#define GATHER_BLOCKS (GBPG * NGROUPS)        // 632

#define CV(H) __builtin_convertvector((H), fv8)

#define ROWSUM16(I0, I1, I2, I3)                                             \
    {                                                                        \
        hv8 h[16];                                                           \
        _Pragma("unroll")                                                    \
        for (int u = 0; u < 4; ++u) {                                        \
            h[u]      = *(const hv8*)(x16 + (size_t)(I0)[u] * D_FEAT + f);   \
            h[4 + u]  = *(const hv8*)(x16 + (size_t)(I1)[u] * D_FEAT + f);   \
            h[8 + u]  = *(const hv8*)(x16 + (size_t)(I2)[u] * D_FEAT + f);   \
            h[12 + u] = *(const hv8*)(x16 + (size_t)(I3)[u] * D_FEAT + f);   \
        }                                                                    \
        fv8 t0 = (CV(h[0]) + CV(h[1])) + (CV(h[2]) + CV(h[3]));              \
        fv8 t1 = (CV(h[4]) + CV(h[5])) + (CV(h[6]) + CV(h[7]));              \
        fv8 t2 = (CV(h[8]) + CV(h[9])) + (CV(h[10]) + CV(h[11]));            \
        fv8 t3 = (CV(h[12]) + CV(h[13])) + (CV(h[14]) + CV(h[15]));          \
        acc += (t0 + t1) + (t2 + t3);                                        \
    }

__global__ __launch_bounds__(256) void gather_kernel(
    const _Float16* __restrict__ x16,
    const int* __restrict__ cursors,   // post-fill: exact per-node counts
    const int* __restrict__ csr,
    const float* __restrict__ deg,
    float* __restrict__ out) {
    const int b = blockIdx.x;
    const int k = b & 7;
    const int r = b >> 3;
    const int g = threadIdx.x >> 4;     // node-in-block 0..15
    const int lane = threadIdx.x & 15;
    const int nig = r * 16 + g;
    if (nig >= NPG) return;
    const int node = k * NPG + nig;
    const int f = lane << 3;            // 8 features per lane

    const int count = cursors[node];
    int j = node * STRIDE;
    const int end = j + count;

    fv8 acc = (fv8)0.0f;

    if (j + 16 <= end) {
        iv4 i0 = *(const iv4*)(csr + j);
        iv4 i1 = *(const iv4*)(csr + j + 4);
        iv4 i2 = *(const iv4*)(csr + j + 8);
        iv4 i3 = *(const iv4*)(csr + j + 12);
        for (; j + 32 <= end; j += 16) {
            iv4 n0 = *(const iv4*)(csr + j + 16);
            iv4 n1 = *(const iv4*)(csr + j + 20);
            iv4 n2 = *(const iv4*)(csr + j + 24);
            iv4 n3 = *(const iv4*)(csr + j + 28);
            ROWSUM16(i0, i1, i2, i3)
            i0 = n0; i1 = n1; i2 = n2; i3 = n3;
        }
        ROWSUM16(i0, i1, i2, i3)
        j += 16;
    }
    for (; j < end; ++j) {
        hv8 h = *(const hv8*)(x16 + (size_t)csr[j] * D_FEAT + f);
        acc += CV(h);
    }

    const float inv = 1.0f / deg[node];
    fv8 rv = acc * inv;
    __builtin_nontemporal_store(rv, (fv8*)(&out[(size_t)node * D_FEAT + f]));
}

extern "C" void kernel_launch(void* const* d_in, const int* in_sizes, int n_in,
                              void* d_out, int out_size, void* d_ws, size_t ws_size,
                              hipStream_t stream) {
    const float* x   = (const float*)d_in[0];
    const int*   ei  = (const int*)d_in[1];   // [2, N_EDGES] flat: src row, dst row
    const float* deg = (const float*)d_in[2];
    float* out = (float*)d_out;

    const int* src = ei;
    const int* dst = ei + N_EDGES;

    char* ws = (char*)d_ws;
    int*       cursors = (int*)(ws + WS_CURSORS);
    int*       csr     = (int*)(ws + WS_CSR);
    _Float16*  x16     = (_Float16*)(ws + WS_X16);

    hipMemsetAsync(cursors, 0, N_NODES * sizeof(int), stream);
    hybrid_kernel<<<HYBRID_BLOCKS, FILL_THREADS, 0, stream>>>(x, x16, src, dst, cursors, csr);
    gather_kernel<<<GATHER_BLOCKS, 256, 0, stream>>>(x16, cursors, csr, deg, out);
}

// Round 14
// 92.450 us; speedup vs baseline: 1.5301x; 1.0259x over previous
//
#include <hip/hip_runtime.h>

#define N_NODES 10000
#define N_EDGES 640000
#define D_FEAT 128
#define NGROUPS 8
#define NPG (N_NODES / NGROUPS)   // 1250
#define STRIDE 256                // padded CSR slots per node (max deg ~112 << 256)
#define QCAP 2048                 // LDS queue capacity (mean 1250, sigma 33)

// ---- ws layout (bytes) ----
#define WS_CURSORS 0                        // int[10000]
#define WS_CSR     40960                    // ushort[2,560,000] = 5.12 MB
#define WS_X16     (40960 + 5120000)        // _Float16[1,280,000] = 2.56 MB

typedef int          iv4 __attribute__((ext_vector_type(4)));
typedef unsigned int uv4 __attribute__((ext_vector_type(4)));
typedef float        fv8 __attribute__((ext_vector_type(8)));
typedef _Float16     hv8 __attribute__((ext_vector_type(8)));

// Hybrid kernel: blocks 0..511 build the CSR (single-scan fill with LDS edge
// queue); remaining blocks run the fp32->fp16 convert concurrently.
#define FILL_THREADS 512
#define FILL_BLOCKS 512
#define NCHUNKS_F 64
#define IV4_PER_CHUNK (N_EDGES / NCHUNKS_F / 4)        // 2500
#define CONV_V8 (N_NODES * D_FEAT / 8)                 // 160000 fv8 elements
#define CONV_BLOCKS ((CONV_V8 + FILL_THREADS - 1) / FILL_THREADS)  // 313
#define HYBRID_BLOCKS (FILL_BLOCKS + CONV_BLOCKS)

__global__ __launch_bounds__(FILL_THREADS) void hybrid_kernel(
    const float* __restrict__ x,
    _Float16* __restrict__ x16,
    const int* __restrict__ src,
    const int* __restrict__ dst,
    int* __restrict__ cursors,
    unsigned short* __restrict__ csr) {
    const int b = blockIdx.x;
    const int t = threadIdx.x;

    if (b >= FILL_BLOCKS) {
        // ---- convert role ----
        const int i = (b - FILL_BLOCKS) * FILL_THREADS + t;
        if (i < CONV_V8) {
            fv8 v = *(const fv8*)(x + (size_t)i * 8);
            *(hv8*)(x16 + (size_t)i * 8) = __builtin_convertvector(v, hv8);
        }
        return;
    }

    // ---- fill role: single-scan fill with LDS edge queue ----
    __shared__ int cnt[NPG];
    __shared__ int base[NPG];
    __shared__ int queue[QCAP];
    __shared__ int qn;
    const int k = b & 7;            // group -> csr slice (XCD-local if %8 maps)
    const int c = b >> 3;           // chunk 0..63
    const int lo = k * NPG;
    const int v0 = c * IV4_PER_CHUNK;
    const int lane = t & 63;

    if (t == 0) qn = 0;
    for (int i = t; i < NPG; i += FILL_THREADS) cnt[i] = 0;
    __syncthreads();

    // Pass A: single scan of dst+src; histogram + ballot-aggregated queue append.
    for (int v = t; v < IV4_PER_CHUNK; v += FILL_THREADS) {
        iv4 d4 = ((const iv4*)dst)[v0 + v];
        iv4 s4 = ((const iv4*)src)[v0 + v];
        #pragma unroll
        for (int kk = 0; kk < 4; ++kk) {
            const int ln = d4[kk] - lo;
            const bool m = ((unsigned)ln < (unsigned)NPG);
            unsigned long long mask = __ballot(m);
            if (mask) {
                const int lead = __ffsll(mask) - 1;
                int qb = 0;
                if (lane == lead) qb = atomicAdd(&qn, __popcll(mask));
                qb = __shfl(qb, lead);
                if (m) {
                    atomicAdd(&cnt[ln], 1);
                    const int my = __popcll(mask & ((1ull << lane) - 1));
                    queue[qb + my] = (ln << 14) | s4[kk];
                }
            }
        }
    }
    __syncthreads();

    const int qtot = qn;

    // Bulk reservation: one global atomic per touched node.
    for (int i = t; i < NPG; i += FILL_THREADS) {
        int cc = cnt[i];
        int off = cc ? atomicAdd(&cursors[lo + i], cc) : 0;
        base[i] = (lo + i) * STRIDE + off;
        cnt[i] = 0;                 // reuse as local cursor
    }
    __syncthreads();

    // Pass B: drain the LDS queue (no global re-reads).
    for (int i = t; i < qtot; i += FILL_THREADS) {
        const int e = queue[i];
        const int ln = e >> 14;
        const int slot = base[ln] + atomicAdd(&cnt[ln], 1);
        csr[slot] = (unsigned short)(e & 0x3FFF);
    }
}

// Gather on fp16 rows with ushort indices: 16 lanes/node, 16 nodes per
// 256-thread block; %8 grouping matches fill so csr + x16 stay XCD-L2-hot.
#define GBPG 79                               // ceil(1250/16)
#define GATHER_BLOCKS (GBPG * NGROUPS)        // 632

#define CV(H) __builtin_convertvector((H), fv8)

#define ROWSUM16(A0, A1)                                                     \
    {                                                                        \
        int ia[8], ib[8];                                                    \
        ia[0] = (A0)[0] & 0xFFFF; ia[1] = (A0)[0] >> 16;                     \
        ia[2] = (A0)[1] & 0xFFFF; ia[3] = (A0)[1] >> 16;                     \
        ia[4] = (A0)[2] & 0xFFFF; ia[5] = (A0)[2] >> 16;                     \
        ia[6] = (A0)[3] & 0xFFFF; ia[7] = (A0)[3] >> 16;                     \
        ib[0] = (A1)[0] & 0xFFFF; ib[1] = (A1)[0] >> 16;                     \
        ib[2] = (A1)[1] & 0xFFFF; ib[3] = (A1)[1] >> 16;                     \
        ib[4] = (A1)[2] & 0xFFFF; ib[5] = (A1)[2] >> 16;                     \
        ib[6] = (A1)[3] & 0xFFFF; ib[7] = (A1)[3] >> 16;                     \
        hv8 h[16];                                                           \
        _Pragma("unroll")                                                    \
        for (int u = 0; u < 8; ++u) {                                        \
            h[u]     = *(const hv8*)(x16 + (size_t)ia[u] * D_FEAT + f);      \
            h[8 + u] = *(const hv8*)(x16 + (size_t)ib[u] * D_FEAT + f);      \
        }                                                                    \
        fv8 t0 = (CV(h[0]) + CV(h[1])) + (CV(h[2]) + CV(h[3]));              \
        fv8 t1 = (CV(h[4]) + CV(h[5])) + (CV(h[6]) + CV(h[7]));              \
        fv8 t2 = (CV(h[8]) + CV(h[9])) + (CV(h[10]) + CV(h[11]));            \
        fv8 t3 = (CV(h[12]) + CV(h[13])) + (CV(h[14]) + CV(h[15]));          \
        acc += (t0 + t1) + (t2 + t3);                                        \
    }

__global__ __launch_bounds__(256) void gather_kernel(
    const _Float16* __restrict__ x16,
    const int* __restrict__ cursors,   // post-fill: exact per-node counts
    const unsigned short* __restrict__ csr,
    const float* __restrict__ deg,
    float* __restrict__ out) {
    const int b = blockIdx.x;
    const int k = b & 7;
    const int r = b >> 3;
    const int g = threadIdx.x >> 4;     // node-in-block 0..15
    const int lane = threadIdx.x & 15;
    const int nig = r * 16 + g;
    if (nig >= NPG) return;
    const int node = k * NPG + nig;
    const int f = lane << 3;            // 8 features per lane

    const int count = cursors[node];
    int j = node * STRIDE;              // ushort units
    const int end = j + count;

    fv8 acc = (fv8)0.0f;

    if (j + 16 <= end) {
        uv4 a0 = *(const uv4*)(csr + j);
        uv4 a1 = *(const uv4*)(csr + j + 8);
        for (; j + 32 <= end; j += 16) {
            uv4 n0 = *(const uv4*)(csr + j + 16);
            uv4 n1 = *(const uv4*)(csr + j + 24);
            ROWSUM16(a0, a1)
            a0 = n0; a1 = n1;
        }
        ROWSUM16(a0, a1)
        j += 16;
    }
    for (; j < end; ++j) {
        hv8 h = *(const hv8*)(x16 + (size_t)csr[j] * D_FEAT + f);
        acc += CV(h);
    }

    const float inv = 1.0f / deg[node];
    fv8 rv = acc * inv;
    __builtin_nontemporal_store(rv, (fv8*)(&out[(size_t)node * D_FEAT + f]));
}

extern "C" void kernel_launch(void* const* d_in, const int* in_sizes, int n_in,
                              void* d_out, int out_size, void* d_ws, size_t ws_size,
                              hipStream_t stream) {
    const float* x   = (const float*)d_in[0];
    const int*   ei  = (const int*)d_in[1];   // [2, N_EDGES] flat: src row, dst row
    const float* deg = (const float*)d_in[2];
    float* out = (float*)d_out;

    const int* src = ei;
    const int* dst = ei + N_EDGES;

    char* ws = (char*)d_ws;
    int*            cursors = (int*)(ws + WS_CURSORS);
    unsigned short* csr     = (unsigned short*)(ws + WS_CSR);
    _Float16*       x16     = (_Float16*)(ws + WS_X16);

    hipMemsetAsync(cursors, 0, N_NODES * sizeof(int), stream);
    hybrid_kernel<<<HYBRID_BLOCKS, FILL_THREADS, 0, stream>>>(x, x16, src, dst, cursors, csr);
    gather_kernel<<<GATHER_BLOCKS, 256, 0, stream>>>(x16, cursors, csr, deg, out);
}